// Round 3
// baseline (2471.232 us; speedup 1.0000x reference)
//
#include <hip/hip_runtime.h>
#include <hip/hip_bf16.h>

// KNN top-16: X_test[4096,256] vs X_train[65536,256], fp32 in, int32 idx out.
// Phase 1: fp32->bf16 convert; fp32 train row sq-norms via numpy-pairwise emulation.
// Phase 2: bf16 MFMA approx score GEMM (v = ||b||^2 - 2 a.b) + per-row top-16 per
//          4096-col train chunk (race-free dump-and-scan). Containment margin
//          ~30 d^2-units vs sigma~0.1 approx noise -> candidates always contain
//          the true (and the fp32-reference's) top-16.
// Phase 3: re-rank 256 candidates/row by EMULATING the reference fp32 pipeline
//          bit-closely: np-pairwise fp32 row norms, sequential-FMA fp32 cross,
//          s32 = fl32(fl32(ta+tb) - 2*c32), d32 = sqrtf(max(s32,0)); lex (d32, idx).
//          (fp32 rounding snaps near-ties to equality -> index tie-break; an exact
//          fp64 ranking provably mismatches the reference on ~10 snapped pairs.)

typedef short bf16x8 __attribute__((ext_vector_type(8)));
typedef float f32x4 __attribute__((ext_vector_type(4)));
typedef unsigned short ushort_t;
typedef unsigned long long u64;

#define K_DIM     256
#define N_TRAIN   65536
#define N_TEST    4096
#define TM        128
#define TN        128
#define NCHUNK    16
#define CHUNK_N   (N_TRAIN / NCHUNK)      // 4096
#define ITERS     (CHUNK_N / TN)          // 32
#define LISTN     16
#define SVP       132                      // sVal row pitch (ushorts)
#define INFF      3.0e38f

// ---------------- numpy pairwise sum emulation (fp32, contract OFF) ----------------
// numpy pairwise_sum for n=256: two 128-blocks (8-accumulator loop each), block
// results added. Squares are separate-rounded fp32 muls (X*X array then sum).
static __device__ __forceinline__ float np_pw_sq128(const float* __restrict__ x) {
    #pragma clang fp contract(off)
    float r0, r1, r2, r3, r4, r5, r6, r7;
    {
        const float4 a = *(const float4*)(x + 0);
        const float4 b = *(const float4*)(x + 4);
        r0 = a.x * a.x; r1 = a.y * a.y; r2 = a.z * a.z; r3 = a.w * a.w;
        r4 = b.x * b.x; r5 = b.y * b.y; r6 = b.z * b.z; r7 = b.w * b.w;
    }
    for (int i = 8; i < 128; i += 8) {
        const float4 a = *(const float4*)(x + i);
        const float4 b = *(const float4*)(x + i + 4);
        r0 = r0 + a.x * a.x; r1 = r1 + a.y * a.y;
        r2 = r2 + a.z * a.z; r3 = r3 + a.w * a.w;
        r4 = r4 + b.x * b.x; r5 = r5 + b.y * b.y;
        r6 = r6 + b.z * b.z; r7 = r7 + b.w * b.w;
    }
    return ((r0 + r1) + (r2 + r3)) + ((r4 + r5) + (r6 + r7));
}

// ---------------- Phase 1a: convert ----------------
static __device__ __forceinline__ ushort_t f2bf(float x) {
    unsigned u = __float_as_uint(x);
    return (ushort_t)((u + 0x7FFFu + ((u >> 16) & 1u)) >> 16);  // RNE
}

__global__ __launch_bounds__(256) void convert_bf16(
    const float* __restrict__ src, ushort_t* __restrict__ dst, int nrows)
{
    const int wid = threadIdx.x >> 6, lane = threadIdx.x & 63;
    const int row = blockIdx.x * 4 + wid;
    if (row >= nrows) return;
    const float4 f = *(const float4*)(src + (size_t)row * K_DIM + lane * 4);
    ushort4 h;
    h.x = f2bf(f.x); h.y = f2bf(f.y); h.z = f2bf(f.z); h.w = f2bf(f.w);
    *(ushort4*)(dst + (size_t)row * K_DIM + lane * 4) = h;
}

// ---------------- Phase 1b: train row norms, numpy-pairwise fp32 ----------------
__global__ __launch_bounds__(256) void train_sq_np(
    const float* __restrict__ train, float* __restrict__ bsq)
{
    const int r = blockIdx.x * 256 + threadIdx.x;
    const float* x = train + (size_t)r * K_DIM;
    bsq[r] = np_pw_sq128(x) + np_pw_sq128(x + 128);
}

// ---------------- Phase 2: approx GEMM + dump-and-scan per-row top-16 ----------------
__global__ __launch_bounds__(256, 2) void knn_approx(
    const ushort_t* __restrict__ testBf, const ushort_t* __restrict__ trainBf,
    const float* __restrict__ bsq, int* __restrict__ cand)
{
    __shared__ __align__(16) ushort_t sA[TM * 64];
    __shared__ __align__(16) ushort_t sB[TN * 64];
    __shared__ __align__(16) ushort_t sVal[64 * SVP];
    __shared__ float sDist[TM * LISTN];
    __shared__ int   sIdx [TM * LISTN];
    __shared__ float sBsq [TN];

    const int tid = threadIdx.x;
    const int bx = blockIdx.x;
    const int chunk = bx & (NCHUNK - 1);
    const int rowTile = bx >> 4;
    const int rowBase = rowTile * TM;
    const int chunkBase = chunk * CHUNK_N;
    const int lane = tid & 63;
    const int wid = tid >> 6;
    const int quad = lane >> 4;
    const int l15 = lane & 15;
    const int wm = wid >> 1, wn = wid & 1;

    if (tid < TM) {
        #pragma unroll
        for (int j = 0; j < LISTN; ++j) {
            sDist[tid * LISTN + j] = INFF;
            sIdx[tid * LISTN + j] = chunkBase + j;
        }
    }
    float own_cut = INFF; int own_arg = 0;

    for (int it = 0; it < ITERS; ++it) {
        const int colBase = chunkBase + it * TN;
        f32x4 acc[4][4] = {};

        #pragma unroll 1
        for (int p = 0; p < 4; ++p) {
            __syncthreads();
            #pragma unroll
            for (int g0 = 0; g0 < 1024; g0 += 256) {
                const int g = g0 + tid;
                const int r = g >> 3, kg = g & 7;
                const uint4 v = *(const uint4*)(testBf + (size_t)(rowBase + r) * K_DIM + p * 64 + kg * 8);
                *(uint4*)(sA + r * 64 + ((kg ^ (r & 7)) << 3)) = v;
            }
            #pragma unroll
            for (int g0 = 0; g0 < 1024; g0 += 256) {
                const int g = g0 + tid;
                const int r = g >> 3, kg = g & 7;
                const uint4 v = *(const uint4*)(trainBf + (size_t)(colBase + r) * K_DIM + p * 64 + kg * 8);
                *(uint4*)(sB + r * 64 + ((kg ^ (r & 7)) << 3)) = v;
            }
            if (p == 0 && tid < TN) sBsq[tid] = bsq[colBase + tid];
            __syncthreads();

            #pragma unroll
            for (int s = 0; s < 2; ++s) {
                bf16x8 af[4], bfr[4];
                #pragma unroll
                for (int im = 0; im < 4; ++im) {
                    const int row = wm * 64 + im * 16 + l15;
                    const int pg = ((s << 2) | quad) ^ (row & 7);
                    af[im] = *(const bf16x8*)(sA + row * 64 + (pg << 3));
                }
                #pragma unroll
                for (int in = 0; in < 4; ++in) {
                    const int col = wn * 64 + in * 16 + l15;
                    const int pg = ((s << 2) | quad) ^ (col & 7);
                    bfr[in] = *(const bf16x8*)(sB + col * 64 + (pg << 3));
                }
                #pragma unroll
                for (int im = 0; im < 4; ++im)
                    #pragma unroll
                    for (int in = 0; in < 4; ++in)
                        acc[im][in] = __builtin_amdgcn_mfma_f32_16x16x32_bf16(
                            af[im], bfr[in], acc[im][in], 0, 0, 0);
            }
        }

        // v = bsq[col] - 2*dot; C layout: row=quad*4+r, col=l15
        float bq[4];
        #pragma unroll
        for (int in = 0; in < 4; ++in) bq[in] = sBsq[wn * 64 + in * 16 + l15];
        #pragma unroll
        for (int im = 0; im < 4; ++im)
            #pragma unroll
            for (int in = 0; in < 4; ++in)
                #pragma unroll
                for (int r = 0; r < 4; ++r)
                    acc[im][in][r] = fmaf(-2.0f, acc[im][in][r], bq[in]);

        #pragma unroll 1
        for (int p2 = 0; p2 < 2; ++p2) {
            __syncthreads();
            #pragma unroll
            for (int im = 0; im < 4; ++im)
                #pragma unroll
                for (int in1 = 0; in1 < 2; ++in1) {
                    const int in = p2 * 2 + in1;
                    const int s = wn * 32 + in1 * 16 + l15;
                    ushort4 pk;
                    pk.x = f2bf(acc[im][in][0]);
                    pk.y = f2bf(acc[im][in][1]);
                    pk.z = f2bf(acc[im][in][2]);
                    pk.w = f2bf(acc[im][in][3]);
                    *(ushort4*)(sVal + s * SVP + wm * 64 + im * 16 + quad * 4) = pk;
                }
            __syncthreads();
            if (tid < TM) {
                for (int s = 0; s < 64; ++s) {
                    const unsigned u = sVal[s * SVP + tid];
                    const float v = __uint_as_float(u << 16);
                    if (v < own_cut) {
                        const int col = colBase + ((s >> 5) << 6) + (p2 << 5) + (s & 31);
                        sDist[tid * LISTN + own_arg] = v;
                        sIdx [tid * LISTN + own_arg] = col;
                        own_cut = sDist[tid * LISTN]; own_arg = 0;
                        #pragma unroll
                        for (int j = 1; j < LISTN; ++j) {
                            const float d = sDist[tid * LISTN + j];
                            if (d > own_cut) { own_cut = d; own_arg = j; }
                        }
                    }
                }
            }
        }
    }

    __syncthreads();
    if (tid < TM) {
        #pragma unroll
        for (int j = 0; j < LISTN; ++j)
            cand[(size_t)(rowBase + tid) * (NCHUNK * LISTN) + chunk * LISTN + j] =
                sIdx[tid * LISTN + j];
    }
}

// ---------------- Phase 3: fp32-reference-emulating re-rank + lex top-16 ----------------
__global__ __launch_bounds__(256) void knn_refine(
    const float* __restrict__ test, const float* __restrict__ train,
    const float* __restrict__ bsq, const int* __restrict__ cand,
    int* __restrict__ out)
{
    __shared__ __align__(16) float sArow[K_DIM];
    __shared__ u64 sKey[256];
    const int row = blockIdx.x, tid = threadIdx.x;
    sArow[tid] = test[(size_t)row * K_DIM + tid];
    const int ci = cand[(size_t)row * 256 + tid];
    __syncthreads();

    // ta32: np-pairwise fp32 (redundant per-thread; LDS broadcast reads are free)
    const float ta = np_pw_sq128(sArow) + np_pw_sq128(sArow + 128);
    const float tb = bsq[ci];

    // c32: sequential fp32 FMA over k ascending (BLAS microkernel accumulation order)
    const float4* bp = (const float4*)(train + (size_t)ci * K_DIM);
    const float4* ap = (const float4*)sArow;
    float c = 0.0f;
    #pragma unroll 4
    for (int k = 0; k < K_DIM / 4; ++k) {
        const float4 a = ap[k];
        const float4 b = bp[k];
        c = fmaf(a.x, b.x, c); c = fmaf(a.y, b.y, c);
        c = fmaf(a.z, b.z, c); c = fmaf(a.w, b.w, c);
    }

    float d32;
    {
        #pragma clang fp contract(off)
        const float t = ta + tb;            // fl32(ta + tb)
        float s = t - 2.0f * c;             // fl32(t - 2*c); 2*c exact
        s = fmaxf(s, 0.0f);
        d32 = sqrtf(s);                     // IEEE-correct sqrtf
    }
    // lex key: nonneg float bits are order-monotone; low 32 = idx (tie -> lower idx)
    sKey[tid] = ((u64)__float_as_uint(d32) << 32) | (unsigned)ci;
    __syncthreads();

    if (tid < 64) {
        u64 ek[4];
        #pragma unroll
        for (int j = 0; j < 4; ++j) ek[j] = sKey[tid * 4 + j];
        for (int sel = 0; sel < 16; ++sel) {
            u64 bk = ek[0];
            #pragma unroll
            for (int j = 1; j < 4; ++j) bk = (ek[j] < bk) ? ek[j] : bk;
            #pragma unroll
            for (int off = 32; off > 0; off >>= 1) {
                const u64 ok = __shfl_down(bk, off);
                bk = (ok < bk) ? ok : bk;
            }
            bk = __shfl(bk, 0);
            if (tid == 0) out[(size_t)row * 16 + sel] = (int)(bk & 0xFFFFFFFFULL);
            #pragma unroll
            for (int j = 0; j < 4; ++j)      // keys unique: winner clears itself
                if (ek[j] == bk) ek[j] = ~0ULL;
        }
    }
}

// ---------------- launch ----------------
extern "C" void kernel_launch(void* const* d_in, const int* in_sizes, int n_in,
                              void* d_out, int out_size, void* d_ws, size_t ws_size,
                              hipStream_t stream)
{
    const float* Xtrain = (const float*)d_in[0];   // [65536, 256]
    const float* Xtest  = (const float*)d_in[1];   // [4096, 256]
    int* out = (int*)d_out;                        // [4096, 16] int32

    const size_t OFF_TRAINBF = 0;                              // 33,554,432 B
    const size_t OFF_TESTBF  = 33554432;                       //  2,097,152 B
    const size_t OFF_BSQ     = 35651584;                       //    262,144 B
    const size_t OFF_CAND    = 35913728;                       //  4,194,304 B
    const size_t NEED        = 40108032;
    if (ws_size < NEED) return;

    char* ws = (char*)d_ws;
    ushort_t* trainBf = (ushort_t*)(ws + OFF_TRAINBF);
    ushort_t* testBf  = (ushort_t*)(ws + OFF_TESTBF);
    float*    bsq     = (float*)(ws + OFF_BSQ);
    int*      cand    = (int*)(ws + OFF_CAND);

    convert_bf16<<<dim3(N_TRAIN / 4), dim3(256), 0, stream>>>(Xtrain, trainBf, N_TRAIN);
    convert_bf16<<<dim3(N_TEST / 4), dim3(256), 0, stream>>>(Xtest, testBf, N_TEST);
    train_sq_np<<<dim3(N_TRAIN / 256), dim3(256), 0, stream>>>(Xtrain, bsq);
    knn_approx<<<dim3((N_TEST / TM) * NCHUNK), dim3(256), 0, stream>>>(testBf, trainBf, bsq, cand);
    knn_refine<<<dim3(N_TEST), dim3(256), 0, stream>>>(Xtest, Xtrain, bsq, cand, out);
}

// Round 5
// 877.086 us; speedup vs baseline: 2.8175x; 2.8175x over previous
//
#include <hip/hip_runtime.h>
#include <hip/hip_bf16.h>

// KNN top-16: X_test[4096,256] vs X_train[65536,256], fp32 in, int32 idx out.
// Phase 1: fp32->bf16 convert; fp32 train row sq-norms via numpy-pairwise emulation.
// Phase 2: bf16 MFMA approx score GEMM (v = ||b||^2 - 2 a.b) + per-row top-16 per
//          4096-col train chunk via PUSH-based selection: producers push rare
//          sub-cutoff values onto per-row LDS stacks; owners keep register-resident
//          sorted-16 lists. NOTE: 64 acc values per thread -> 64-BIT pending mask
//          (round 4's 32-bit mask hit 1u<<63 UB -> hang/abort).
// Phase 3: re-rank 256 candidates/row by emulating the reference fp32 pipeline
//          (np-pairwise norms, sequential-FMA cross, fl32 combine, sqrtf) and
//          lex (d32, idx) top-16 — fp32 snap-ties resolve by index, matching top_k.

typedef short bf16x8 __attribute__((ext_vector_type(8)));
typedef float f32x4 __attribute__((ext_vector_type(4)));
typedef unsigned short ushort_t;
typedef unsigned long long u64;

#define K_DIM     256
#define N_TRAIN   65536
#define N_TEST    4096
#define TM        128
#define TN        128
#define NCHUNK    16
#define CHUNK_N   (N_TRAIN / NCHUNK)      // 4096
#define ITERS     (CHUNK_N / TN)          // 32
#define LISTN     16
#define QCAP      32
#define INFF      3.0e38f

// ---------------- numpy pairwise sum emulation (fp32, contract OFF) ----------------
static __device__ __forceinline__ float np_pw_sq128(const float* __restrict__ x) {
    #pragma clang fp contract(off)
    float r0, r1, r2, r3, r4, r5, r6, r7;
    {
        const float4 a = *(const float4*)(x + 0);
        const float4 b = *(const float4*)(x + 4);
        r0 = a.x * a.x; r1 = a.y * a.y; r2 = a.z * a.z; r3 = a.w * a.w;
        r4 = b.x * b.x; r5 = b.y * b.y; r6 = b.z * b.z; r7 = b.w * b.w;
    }
    for (int i = 8; i < 128; i += 8) {
        const float4 a = *(const float4*)(x + i);
        const float4 b = *(const float4*)(x + i + 4);
        r0 = r0 + a.x * a.x; r1 = r1 + a.y * a.y;
        r2 = r2 + a.z * a.z; r3 = r3 + a.w * a.w;
        r4 = r4 + b.x * b.x; r5 = r5 + b.y * b.y;
        r6 = r6 + b.z * b.z; r7 = r7 + b.w * b.w;
    }
    return ((r0 + r1) + (r2 + r3)) + ((r4 + r5) + (r6 + r7));
}

// ---------------- Phase 1a: convert ----------------
static __device__ __forceinline__ ushort_t f2bf(float x) {
    unsigned u = __float_as_uint(x);
    return (ushort_t)((u + 0x7FFFu + ((u >> 16) & 1u)) >> 16);  // RNE
}

__global__ __launch_bounds__(256) void convert_bf16(
    const float* __restrict__ src, ushort_t* __restrict__ dst, int nrows)
{
    const int wid = threadIdx.x >> 6, lane = threadIdx.x & 63;
    const int row = blockIdx.x * 4 + wid;
    if (row >= nrows) return;
    const float4 f = *(const float4*)(src + (size_t)row * K_DIM + lane * 4);
    ushort4 h;
    h.x = f2bf(f.x); h.y = f2bf(f.y); h.z = f2bf(f.z); h.w = f2bf(f.w);
    *(ushort4*)(dst + (size_t)row * K_DIM + lane * 4) = h;
}

// ---------------- Phase 1b: train row norms, numpy-pairwise fp32 ----------------
__global__ __launch_bounds__(256) void train_sq_np(
    const float* __restrict__ train, float* __restrict__ bsq)
{
    const int r = blockIdx.x * 256 + threadIdx.x;
    const float* x = train + (size_t)r * K_DIM;
    bsq[r] = np_pw_sq128(x) + np_pw_sq128(x + 128);
}

// ---------------- Phase 2: approx GEMM + push-based per-row top-16 ----------------
__global__ __launch_bounds__(256, 2) void knn_approx(
    const ushort_t* __restrict__ testBf, const ushort_t* __restrict__ trainBf,
    const float* __restrict__ bsq, int* __restrict__ cand)
{
    __shared__ __align__(16) ushort_t sA[TM * 64];
    __shared__ __align__(16) ushort_t sB[TN * 64];
    __shared__ float sQv [TM * QCAP];
    __shared__ int   sQc [TM * QCAP];
    __shared__ int   sQn [TM];
    __shared__ float sCut[TM];
    __shared__ float sBsq[TN];

    const int tid = threadIdx.x;
    const int bx = blockIdx.x;
    const int chunk = bx & (NCHUNK - 1);
    const int rowTile = bx >> 4;
    const int rowBase = rowTile * TM;
    const int chunkBase = chunk * CHUNK_N;
    const int lane = tid & 63;
    const int wid = tid >> 6;
    const int quad = lane >> 4;
    const int l15 = lane & 15;
    const int wm = wid >> 1, wn = wid & 1;

    if (tid < TM) { sQn[tid] = 0; sCut[tid] = INFF; }

    // owner (tid<128) register-resident sorted-ascending top-16 list
    float lv[LISTN]; int lc[LISTN];
    #pragma unroll
    for (int j = 0; j < LISTN; ++j) { lv[j] = INFF; lc[j] = chunkBase + j; }

    for (int it = 0; it < ITERS; ++it) {
        const int colBase = chunkBase + it * TN;
        f32x4 acc[4][4] = {};

        #pragma unroll 1
        for (int p = 0; p < 4; ++p) {
            __syncthreads();   // also covers sQn/sCut init visibility at it=0
            #pragma unroll
            for (int g0 = 0; g0 < 1024; g0 += 256) {
                const int g = g0 + tid;
                const int r = g >> 3, kg = g & 7;
                const uint4 v = *(const uint4*)(testBf + (size_t)(rowBase + r) * K_DIM + p * 64 + kg * 8);
                *(uint4*)(sA + r * 64 + ((kg ^ (r & 7)) << 3)) = v;
            }
            #pragma unroll
            for (int g0 = 0; g0 < 1024; g0 += 256) {
                const int g = g0 + tid;
                const int r = g >> 3, kg = g & 7;
                const uint4 v = *(const uint4*)(trainBf + (size_t)(colBase + r) * K_DIM + p * 64 + kg * 8);
                *(uint4*)(sB + r * 64 + ((kg ^ (r & 7)) << 3)) = v;
            }
            if (p == 0 && tid < TN) sBsq[tid] = bsq[colBase + tid];
            __syncthreads();

            #pragma unroll
            for (int s = 0; s < 2; ++s) {
                bf16x8 af[4], bfr[4];
                #pragma unroll
                for (int im = 0; im < 4; ++im) {
                    const int row = wm * 64 + im * 16 + l15;
                    const int pg = ((s << 2) | quad) ^ (row & 7);
                    af[im] = *(const bf16x8*)(sA + row * 64 + (pg << 3));
                }
                #pragma unroll
                for (int in = 0; in < 4; ++in) {
                    const int col = wn * 64 + in * 16 + l15;
                    const int pg = ((s << 2) | quad) ^ (col & 7);
                    bfr[in] = *(const bf16x8*)(sB + col * 64 + (pg << 3));
                }
                #pragma unroll
                for (int im = 0; im < 4; ++im)
                    #pragma unroll
                    for (int in = 0; in < 4; ++in)
                        acc[im][in] = __builtin_amdgcn_mfma_f32_16x16x32_bf16(
                            af[im], bfr[in], acc[im][in], 0, 0, 0);
            }
        }

        // v = bsq[col] - 2*dot; C layout: row=quad*4+r, col=l15
        float bq[4];
        #pragma unroll
        for (int in = 0; in < 4; ++in) bq[in] = sBsq[wn * 64 + in * 16 + l15];
        #pragma unroll
        for (int im = 0; im < 4; ++im)
            #pragma unroll
            for (int in = 0; in < 4; ++in)
                #pragma unroll
                for (int r = 0; r < 4; ++r)
                    acc[im][in][r] = fmaf(-2.0f, acc[im][in][r], bq[in]);

        // ---- push-based selection; bounded retry rounds on stack overflow ----
        // 64 values per thread -> 64-bit pending mask (1ULL shifts; no UB)
        u64 pend = ~0ULL;
        while (true) {
            u64 np = 0ULL;
            #pragma unroll
            for (int im = 0; im < 4; ++im)
                #pragma unroll
                for (int in = 0; in < 4; ++in)
                    #pragma unroll
                    for (int r = 0; r < 4; ++r) {
                        const int bitIdx = (im * 4 + in) * 4 + r;
                        if ((pend >> bitIdx) & 1ULL) {
                            const int row = wm * 64 + im * 16 + quad * 4 + r;
                            const float v = acc[im][in][r];
                            if (v < sCut[row]) {    // broadcast LDS read (4 addrs/wave)
                                const int pos = atomicAdd(&sQn[row], 1);
                                if (pos < QCAP) {
                                    sQv[row * QCAP + pos] = v;
                                    sQc[row * QCAP + pos] = colBase + wn * 64 + in * 16 + l15;
                                } else {
                                    np |= (1ULL << bitIdx);  // stack full: retry
                                }
                            }
                        }
                    }
            __syncthreads();                        // pushes done before drain
            if (tid < TM) {                         // owner drains its stack -> reg list
                const int n = min(sQn[tid], QCAP);
                for (int e = 0; e < n; ++e) {
                    const float v = sQv[tid * QCAP + e];
                    if (v < lv[LISTN - 1]) {
                        lv[LISTN - 1] = v; lc[LISTN - 1] = sQc[tid * QCAP + e];
                        #pragma unroll
                        for (int j = LISTN - 1; j > 0; --j)
                            if (lv[j] < lv[j - 1]) {
                                const float tv = lv[j]; lv[j] = lv[j - 1]; lv[j - 1] = tv;
                                const int tc = lc[j]; lc[j] = lc[j - 1]; lc[j - 1] = tc;
                            }
                    }
                }
                sQn[tid] = 0;
                sCut[tid] = lv[LISTN - 1];
            }
            if (!__syncthreads_or(np != 0ULL)) break; // also publishes sCut/sQn
            pend = np;
        }
    }

    if (tid < TM) {
        #pragma unroll
        for (int j = 0; j < LISTN; ++j)
            cand[(size_t)(rowBase + tid) * (NCHUNK * LISTN) + chunk * LISTN + j] = lc[j];
    }
}

// ---------------- Phase 3: fp32-reference-emulating re-rank + lex top-16 ----------------
__global__ __launch_bounds__(256) void knn_refine(
    const float* __restrict__ test, const float* __restrict__ train,
    const float* __restrict__ bsq, const int* __restrict__ cand,
    int* __restrict__ out)
{
    __shared__ __align__(16) float sArow[K_DIM];
    __shared__ u64 sKey[256];
    const int row = blockIdx.x, tid = threadIdx.x;
    sArow[tid] = test[(size_t)row * K_DIM + tid];
    const int ci = cand[(size_t)row * 256 + tid];
    __syncthreads();

    const float ta = np_pw_sq128(sArow) + np_pw_sq128(sArow + 128);
    const float tb = bsq[ci];

    const float4* bp = (const float4*)(train + (size_t)ci * K_DIM);
    const float4* ap = (const float4*)sArow;
    float c = 0.0f;
    #pragma unroll 4
    for (int k = 0; k < K_DIM / 4; ++k) {
        const float4 a = ap[k];
        const float4 b = bp[k];
        c = fmaf(a.x, b.x, c); c = fmaf(a.y, b.y, c);
        c = fmaf(a.z, b.z, c); c = fmaf(a.w, b.w, c);
    }

    float d32;
    {
        #pragma clang fp contract(off)
        const float t = ta + tb;
        float s = t - 2.0f * c;
        s = fmaxf(s, 0.0f);
        d32 = sqrtf(s);
    }
    sKey[tid] = ((u64)__float_as_uint(d32) << 32) | (unsigned)ci;
    __syncthreads();

    if (tid < 64) {
        u64 ek[4];
        #pragma unroll
        for (int j = 0; j < 4; ++j) ek[j] = sKey[tid * 4 + j];
        for (int sel = 0; sel < 16; ++sel) {
            u64 bk = ek[0];
            #pragma unroll
            for (int j = 1; j < 4; ++j) bk = (ek[j] < bk) ? ek[j] : bk;
            #pragma unroll
            for (int off = 32; off > 0; off >>= 1) {
                const u64 ok = __shfl_down(bk, off);
                bk = (ok < bk) ? ok : bk;
            }
            bk = __shfl(bk, 0);
            if (tid == 0) out[(size_t)row * 16 + sel] = (int)(bk & 0xFFFFFFFFULL);
            #pragma unroll
            for (int j = 0; j < 4; ++j)
                if (ek[j] == bk) ek[j] = ~0ULL;
        }
    }
}

// ---------------- launch ----------------
extern "C" void kernel_launch(void* const* d_in, const int* in_sizes, int n_in,
                              void* d_out, int out_size, void* d_ws, size_t ws_size,
                              hipStream_t stream)
{
    const float* Xtrain = (const float*)d_in[0];   // [65536, 256]
    const float* Xtest  = (const float*)d_in[1];   // [4096, 256]
    int* out = (int*)d_out;                        // [4096, 16] int32

    const size_t OFF_TRAINBF = 0;                              // 33,554,432 B
    const size_t OFF_TESTBF  = 33554432;                       //  2,097,152 B
    const size_t OFF_BSQ     = 35651584;                       //    262,144 B
    const size_t OFF_CAND    = 35913728;                       //  4,194,304 B
    const size_t NEED        = 40108032;
    if (ws_size < NEED) return;

    char* ws = (char*)d_ws;
    ushort_t* trainBf = (ushort_t*)(ws + OFF_TRAINBF);
    ushort_t* testBf  = (ushort_t*)(ws + OFF_TESTBF);
    float*    bsq     = (float*)(ws + OFF_BSQ);
    int*      cand    = (int*)(ws + OFF_CAND);

    convert_bf16<<<dim3(N_TRAIN / 4), dim3(256), 0, stream>>>(Xtrain, trainBf, N_TRAIN);
    convert_bf16<<<dim3(N_TEST / 4), dim3(256), 0, stream>>>(Xtest, testBf, N_TEST);
    train_sq_np<<<dim3(N_TRAIN / 256), dim3(256), 0, stream>>>(Xtrain, bsq);
    knn_approx<<<dim3((N_TEST / TM) * NCHUNK), dim3(256), 0, stream>>>(testBf, trainBf, bsq, cand);
    knn_refine<<<dim3(N_TEST), dim3(256), 0, stream>>>(Xtest, Xtrain, bsq, cand, out);
}